// Round 8
// baseline (148.472 us; speedup 1.0000x reference)
//
#include <hip/hip_runtime.h>
#include <hip/hip_bf16.h>
#include <cstdint>

// Problem dims (fixed by reference)
#define B_  16
#define N_  32
#define L_  2048
#define D_  16
#define M_  32
#define K_  3
#define W_  2046   // (L - K)/STRIDE + 1

typedef __bf16 bf16x8 __attribute__((ext_vector_type(8)));
typedef float  f32x4  __attribute__((ext_vector_type(4)));

union frag_cast { uint4 u; bf16x8 f; };

// pack two fp32 -> one u32 holding two RTNE bf16 (a in low half)
__device__ __forceinline__ uint32_t pk2(float a, float b) {
    __hip_bfloat162 p = __float22bfloat162_rn(make_float2(a, b));
    union { __hip_bfloat162 h; uint32_t u; } cv; cv.h = p; return cv.u;
}

// async 16-B global->LDS (direct-to-shared DMA; wave-uniform dest + lane*16,
// per-lane source — verified pattern from R10/R11/R12)
__device__ __forceinline__ void gload_lds16(const float* g, void* l) {
    __builtin_amdgcn_global_load_lds(
        (const __attribute__((address_space(1))) unsigned int*)g,
        (__attribute__((address_space(3))) unsigned int*)l, 16, 0, 0);
}

// ---------------------------------------------------------------------------
// Setup: transpose + scale weights into MFMA B-fragment order in d_ws.
// (ROUND-3/5 VERIFIED MAPPING — values unchanged.)
// ws layout: uint4[ct(8)][kc(12)][lane(64)]; lane's uint4 = 8 bf16 =
// B[κ = kc*32 + (lane>>4)*8 + j][col = ct*16 + (lane&15)], j = 0..7.
// ---------------------------------------------------------------------------
__global__ __launch_bounds__(64) void caps_setup(const float* __restrict__ wp,
                                                 uint2* __restrict__ ws2) {
    const int gid  = blockIdx.x * 64 + threadIdx.x;   // 0..12287
    const int i    = gid >> 1;                        // uint4 index 0..6143
    const int half = gid & 1;
    const int ct   = i / 768;
    const int rem  = i - ct * 768;
    const int kc   = rem >> 6;
    const int lane = rem & 63;
    const int q    = lane >> 4;
    const int col  = (ct << 4) | (lane & 15);
    const int m = col >> 2, d = col & 3;
    const int k = kc >> 2;
    const int n = (kc & 3) * 8 + q * 2 + half;
    float f[4];
#pragma unroll
    for (int x = 0; x < 4; ++x)
        f[x] = wp[(((k * 32 + n) * 4 + x) * 4 + d) * 32 + m] * 0.03125f;
    uint2 o;
    o.x = pk2(f[0], f[1]); o.y = pk2(f[2], f[3]);
    ws2[i * 2 + half] = o;
}

// LDS regions (single copy = 31232 B -> 4 blocks/CU):
//  f32 stage: byte(n,w,a) = n*640 + w*64 + a*16, n=0..31, w=0..9, a=0..3
//             = 20480 B = EXACTLY 20 linear 1024-B DMA chunks, zero padding
//  bf16 tile (VERIFIED layout, stride 1184->672; 672/4 % 32 = 8 = identical
//             q bank-stagger): byte = n2*672 + w*64 + a*16 (+8 for odd n)
#define XF32ROW 640
#define XF32SZ  20480
#define XBFOFF  20480
#define XSTRIDE_N2 672
#define LDS_TOTAL (XF32SZ + 16 * XSTRIDE_N2)   // 31232 B

// ---------------------------------------------------------------------------
// R13 = R12 structure at 4 blocks/CU.  Slab 16w -> 8w (4 slabs x 8 w per
// block, same 32-w super-tile, same grid (64,16) = 1024 blocks = EXACTLY
// 4/CU x 256 CU resident -> single round, no convoy, 16 waves/CU.
//  - staging: 20 DMA chunks/slab, zero regs/VALU, prefetch of slab s+1
//    issued after repack barrier, drained by end-of-slab barrier
//  - repack: once per element per block, off the MFMA critical path
//  - breg: [2][6] + midpoint reload (48 VGPR, fits the 128-VGPR budget of
//    launch_bounds(256,4); R3 showed persistent 96 VGPR spills here)
//  - K-loop: pure bf16 LDS + MFMA (VERIFIED immediates, 672-stride)
//  - stores: VERIFIED 4x4 quad-lane transpose -> one dwordx4 each
// ---------------------------------------------------------------------------
__global__ __launch_bounds__(256, 4) void caps_mfma(
    const float* __restrict__ xp,   // [B][N][L][16] f32
    const uint4* __restrict__ ws,   // B frags
    const float* __restrict__ gp,   // [16]
    const float* __restrict__ bp,   // [16]
    float* __restrict__ out)        // [B][M][W][16]
{
    __shared__ __align__(16) unsigned char xs[LDS_TOTAL];

    const int tid  = threadIdx.x;
    const int wave = tid >> 6;
    const int lane = tid & 63;
    const int q    = lane >> 4;
    const int l15  = lane & 15;
    const int dL   = lane & 3;
    const int msub = (lane >> 2) & 3;
    const int b    = blockIdx.y;
    const int W0   = blockIdx.x * 32;  // 32-w super-tile (4 slabs x 8 w)
    const int ct0  = wave * 2;

    const float* xb = xp + (size_t)b * N_ * L_ * D_;

    // ---- DMA chunk geometry (slab-independent): ch = 4i+wave, 5/wave ----
    int srcf[5];   // float offset n*32768 + a*4  (gw*16 added per slab)
    int wrow[5];   // w row 0..9
#pragma unroll
    for (int i = 0; i < 5; ++i) {
        const int ch   = 4 * i + wave;            // 0..19, all valid
        const int dest = ch * 1024 + lane * 16;
        const int n    = dest / XF32ROW;
        const int rem  = dest - n * XF32ROW;
        wrow[i] = rem >> 6;
        srcf[i] = n * 32768 + ((rem >> 4) & 3) * 4;
    }

    auto issue = [&](int s) {
#pragma unroll
        for (int i = 0; i < 5; ++i) {
            int gw = W0 + s * 8 + wrow[i];
            if (gw > L_ - 1) gw = L_ - 1;          // halo clamp
            gload_lds16(xb + srcf[i] + gw * 16,
                        &xs[(4 * i + wave) * 1024 + lane * 16]);
        }
    };

    // ---- repack geometry: granule g = (n2*10+w)*4+a, 640 over 256 thr ----
    int  rdE[3], wrO[3];
    bool gval[3];
#pragma unroll
    for (int it = 0; it < 3; ++it) {
        const int g = it * 256 + tid;
        gval[it] = (it < 2) || (g < 640);
        const int gg  = g < 640 ? g : 639;
        const int n2  = gg / 40;
        const int rem = gg - n2 * 40;
        const int w   = rem >> 2;
        const int a   = rem & 3;
        rdE[it] = (2 * n2) * XF32ROW + w * 64 + a * 16;   // even-row read
        wrO[it] = n2 * XSTRIDE_N2 + w * 64 + a * 16;      // bf16 granule write
    }

    // f32 LDS -> VERIFIED bf16 granule {even 4 floats, odd 4 floats}
    auto repack = [&]() {
#pragma unroll
        for (int it = 0; it < 3; ++it) if (gval[it]) {
            const f32x4 e = *reinterpret_cast<const f32x4*>(&xs[rdE[it]]);
            const f32x4 o = *reinterpret_cast<const f32x4*>(&xs[rdE[it] + XF32ROW]);
            uint4 u;
            u.x = pk2(e[0], e[1]); u.y = pk2(e[2], e[3]);
            u.z = pk2(o[0], o[1]); u.w = pk2(o[2], o[3]);
            *reinterpret_cast<uint4*>(&xs[XBFOFF + wrO[it]]) = u;
        }
    };

    // ---- prologue: async slab-0 stage + breg(j=0..5) + gamma/beta ----
    issue(0);

    uint4 breg[2][6];                              // 48 VGPR
#pragma unroll
    for (int cp = 0; cp < 2; ++cp)
#pragma unroll
        for (int j = 0; j < 6; ++j)
            breg[cp][j] = ws[(ct0 + cp) * 768 + j * 64 + lane];

    float gmv[4], btv[4];
#pragma unroll
    for (int r = 0; r < 4; ++r) { gmv[r] = gp[r * 4 + dL]; btv[r] = bp[r * 4 + dL]; }

    __syncthreads();   // drains DMA -> slab-0 f32 image complete

    // per-lane bf16 A base (VERIFIED): offsets kn*2688 + k*64 + rt*256
    const unsigned char* ap =
        &xs[XBFOFF + q * XSTRIDE_N2 + (l15 >> 2) * 64 + (l15 & 3) * 16];

#pragma unroll
    for (int s = 0; s < 4; ++s) {
        repack();
        __syncthreads();                           // bf16 ready; f32 buf free

        if (s < 3) {
            issue(s + 1);                          // async prefetch next slab
            __builtin_amdgcn_sched_barrier(0);     // pin issue before K-loop
        }

        if (s > 0) {                               // restore breg j = 0..5
#pragma unroll
            for (int cp = 0; cp < 2; ++cp)
#pragma unroll
                for (int j = 0; j < 6; ++j)
                    breg[cp][j] = ws[(ct0 + cp) * 768 + j * 64 + lane];
        }

        f32x4 acc[2][2];
#pragma unroll
        for (int rt = 0; rt < 2; ++rt)
#pragma unroll
            for (int cp = 0; cp < 2; ++cp)
                acc[rt][cp] = (f32x4){0.f, 0.f, 0.f, 0.f};

        // ---- K-loop first half: kc = 0..5 ----
#pragma unroll
        for (int kc = 0; kc < 6; ++kc) {
            const int k  = kc >> 2;
            const int kn = kc & 3;
            bf16x8 afr[2];
#pragma unroll
            for (int rt = 0; rt < 2; ++rt) {
                frag_cast c;
                c.u = *reinterpret_cast<const uint4*>(
                    ap + kn * 2688 + k * 64 + rt * 256);
                afr[rt] = c.f;
            }
#pragma unroll
            for (int cp = 0; cp < 2; ++cp) {
                frag_cast bc; bc.u = breg[cp][kc];
#pragma unroll
                for (int rt = 0; rt < 2; ++rt)
                    acc[rt][cp] = __builtin_amdgcn_mfma_f32_16x16x32_bf16(
                        afr[rt], bc.f, acc[rt][cp], 0, 0, 0);
            }
        }

        // ---- midpoint: breg <- j = 6..11 (L2-hot, hidden by 16 waves/CU) --
#pragma unroll
        for (int cp = 0; cp < 2; ++cp)
#pragma unroll
            for (int j = 0; j < 6; ++j)
                breg[cp][j] = ws[(ct0 + cp) * 768 + (6 + j) * 64 + lane];

        // ---- K-loop second half: kc = 6..11 ----
#pragma unroll
        for (int j2 = 0; j2 < 6; ++j2) {
            const int kc = 6 + j2;
            const int k  = kc >> 2;
            const int kn = kc & 3;
            bf16x8 afr[2];
#pragma unroll
            for (int rt = 0; rt < 2; ++rt) {
                frag_cast c;
                c.u = *reinterpret_cast<const uint4*>(
                    ap + kn * 2688 + k * 64 + rt * 256);
                afr[rt] = c.f;
            }
#pragma unroll
            for (int cp = 0; cp < 2; ++cp) {
                frag_cast bc; bc.u = breg[cp][j2];
#pragma unroll
                for (int rt = 0; rt < 2; ++rt)
                    acc[rt][cp] = __builtin_amdgcn_mfma_f32_16x16x32_bf16(
                        afr[rt], bc.f, acc[rt][cp], 0, 0, 0);
            }
        }

        // ---- fused LayerNorm (VERIFIED) + 4x4 quad transpose + dwordx4 ----
#pragma unroll
        for (int rt = 0; rt < 2; ++rt) {
            const int wv = W0 + s * 8 + rt * 4 + q;
#pragma unroll
            for (int cp = 0; cp < 2; ++cp) {
                const f32x4 v = acc[rt][cp];
                float ss = v[0] + v[1] + v[2] + v[3];
                float sq = v[0]*v[0] + v[1]*v[1] + v[2]*v[2] + v[3]*v[3];
                ss += __shfl_xor(ss, 1); ss += __shfl_xor(ss, 2);
                sq += __shfl_xor(sq, 1); sq += __shfl_xor(sq, 2);
                const float mu   = ss * (1.f / 16.f);
                const float var  = sq * (1.f / 16.f) - mu * mu;
                const float rstd = rsqrtf(var + 1e-5f);
                float y[4];
#pragma unroll
                for (int r = 0; r < 4; ++r)
                    y[r] = gmv[r] * (v[r] - mu) * rstd + btv[r];
                // 4x4 transpose over (dL, r): lane dL -> dout 4dL..4dL+3
#pragma unroll
                for (int mm = 1; mm <= 2; mm <<= 1) {
                    float p[4];
#pragma unroll
                    for (int r = 0; r < 4; ++r) p[r] = __shfl_xor(y[r], mm);
#pragma unroll
                    for (int r = 0; r < 4; ++r)
                        y[r] = ((dL ^ r) & mm) ? p[r ^ mm] : y[r];
                }
                if (wv < W_) {
                    const int m = (ct0 + cp) * 4 + msub;
                    float4* op = (float4*)(out +
                        ((size_t)(b * M_ + m) * W_ + wv) * D_ + dL * 4);
                    *op = make_float4(y[0], y[1], y[2], y[3]);
                }
            }
        }

        if (s < 3) __syncthreads();  // drains DMA (next f32 image) +
                                     // protects bf16 buf from next repack
    }
}

extern "C" void kernel_launch(void* const* d_in, const int* in_sizes, int n_in,
                              void* d_out, int out_size, void* d_ws, size_t ws_size,
                              hipStream_t stream) {
    const float* x  = (const float*)d_in[0];
    const float* w  = (const float*)d_in[1];
    const float* g  = (const float*)d_in[2];
    const float* be = (const float*)d_in[3];
    float* out = (float*)d_out;

    caps_setup<<<192, 64, 0, stream>>>(w, (uint2*)d_ws);
    caps_mfma<<<dim3(64, 16), 256, 0, stream>>>(
        x, (const uint4*)d_ws, g, be, out);
}

// Round 9
// 137.454 us; speedup vs baseline: 1.0802x; 1.0802x over previous
//
#include <hip/hip_runtime.h>
#include <hip/hip_bf16.h>
#include <cstdint>

// Problem dims (fixed by reference)
#define B_  16
#define N_  32
#define L_  2048
#define D_  16
#define M_  32
#define K_  3
#define W_  2046   // (L - K)/STRIDE + 1

typedef __bf16 bf16x8 __attribute__((ext_vector_type(8)));
typedef float  f32x4  __attribute__((ext_vector_type(4)));

union frag_cast { uint4 u; bf16x8 f; };

// pack two fp32 -> one u32 holding two RTNE bf16 (a in low half)
__device__ __forceinline__ uint32_t pk2(float a, float b) {
    __hip_bfloat162 p = __float22bfloat162_rn(make_float2(a, b));
    union { __hip_bfloat162 h; uint32_t u; } cv; cv.h = p; return cv.u;
}

// async 16-B global->LDS (direct-to-shared DMA; wave-uniform dest + lane*16,
// per-lane source — verified pattern from R10/R11/R12/R13)
__device__ __forceinline__ void gload_lds16(const float* g, void* l) {
    __builtin_amdgcn_global_load_lds(
        (const __attribute__((address_space(1))) unsigned int*)g,
        (__attribute__((address_space(3))) unsigned int*)l, 16, 0, 0);
}

// ---------------------------------------------------------------------------
// Setup: transpose + scale weights into MFMA B-fragment order in d_ws.
// (ROUND-3/5 VERIFIED MAPPING — values unchanged.)
// ws layout: uint4[ct(8)][kc(12)][lane(64)]; lane's uint4 = 8 bf16 =
// B[κ = kc*32 + (lane>>4)*8 + j][col = ct*16 + (lane&15)], j = 0..7.
// ---------------------------------------------------------------------------
__global__ __launch_bounds__(64) void caps_setup(const float* __restrict__ wp,
                                                 uint2* __restrict__ ws2) {
    const int gid  = blockIdx.x * 64 + threadIdx.x;   // 0..12287
    const int i    = gid >> 1;                        // uint4 index 0..6143
    const int half = gid & 1;
    const int ct   = i / 768;
    const int rem  = i - ct * 768;
    const int kc   = rem >> 6;
    const int lane = rem & 63;
    const int q    = lane >> 4;
    const int col  = (ct << 4) | (lane & 15);
    const int m = col >> 2, d = col & 3;
    const int k = kc >> 2;
    const int n = (kc & 3) * 8 + q * 2 + half;
    float f[4];
#pragma unroll
    for (int x = 0; x < 4; ++x)
        f[x] = wp[(((k * 32 + n) * 4 + x) * 4 + d) * 32 + m] * 0.03125f;
    uint2 o;
    o.x = pk2(f[0], f[1]); o.y = pk2(f[2], f[3]);
    ws2[i * 2 + half] = o;
}

// LDS regions (single copy = 31232 B -> 4 blocks/CU):
//  f32 stage: byte(n,w,a) = n*640 + w*64 + a*16, n=0..31, w=0..9, a=0..3
//             = 20480 B = EXACTLY 20 linear 1024-B DMA chunks, zero padding
//  bf16 tile (R8-HARNESS-VERIFIED 672-stride variant of the R3/R5 layout):
//             byte = n2*672 + w*64 + a*16 (+8 for odd n)
#define XF32ROW 640
#define XF32SZ  20480
#define XBFOFF  20480
#define XSTRIDE_N2 672
#define LDS_TOTAL (XF32SZ + 16 * XSTRIDE_N2)   // 31232 B

// ---------------------------------------------------------------------------
// R14 = R13 with the register allocator PINNED.
// R13's regression was VGPR=64: launch_bounds(256,4) only sets MIN waves/EU,
// the allocator targeted 8 waves/EU, squeezed to 64 VGPR and spilled
// (WRITE_SIZE 65.5->72.6 MB).  amdgpu_waves_per_eu(4,4) pins min=max=4 ->
// 128-VGPR budget, live set ~115 fits, no spill, 4 blocks/CU resident
// (16 waves/CU), all 1024 blocks in one round.
// Also: alternating kc-half order per slab — the breg half loaded at the
// previous slab's midpoint is consumed FIRST, so per-slab restores vanish
// (breg load groups per block: 96 -> 60 loads/thread).
// ---------------------------------------------------------------------------
__global__ __launch_bounds__(256)
__attribute__((amdgpu_waves_per_eu(4, 4)))
void caps_mfma(
    const float* __restrict__ xp,   // [B][N][L][16] f32
    const uint4* __restrict__ ws,   // B frags
    const float* __restrict__ gp,   // [16]
    const float* __restrict__ bp,   // [16]
    float* __restrict__ out)        // [B][M][W][16]
{
    __shared__ __align__(16) unsigned char xs[LDS_TOTAL];

    const int tid  = threadIdx.x;
    const int wave = tid >> 6;
    const int lane = tid & 63;
    const int q    = lane >> 4;
    const int l15  = lane & 15;
    const int dL   = lane & 3;
    const int msub = (lane >> 2) & 3;
    const int b    = blockIdx.y;
    const int W0   = blockIdx.x * 32;  // 32-w super-tile (4 slabs x 8 w)
    const int ct0  = wave * 2;

    const float* xb = xp + (size_t)b * N_ * L_ * D_;

    // ---- DMA chunk geometry (slab-independent): ch = 4i+wave, 5/wave ----
    int srcf[5];   // float offset n*32768 + a*4  (gw*16 added per slab)
    int wrow[5];   // w row 0..9
#pragma unroll
    for (int i = 0; i < 5; ++i) {
        const int ch   = 4 * i + wave;            // 0..19, all valid
        const int dest = ch * 1024 + lane * 16;
        const int n    = dest / XF32ROW;
        const int rem  = dest - n * XF32ROW;
        wrow[i] = rem >> 6;
        srcf[i] = n * 32768 + ((rem >> 4) & 3) * 4;
    }

    auto issue = [&](int s) {
#pragma unroll
        for (int i = 0; i < 5; ++i) {
            int gw = W0 + s * 8 + wrow[i];
            if (gw > L_ - 1) gw = L_ - 1;          // halo clamp
            gload_lds16(xb + srcf[i] + gw * 16,
                        &xs[(4 * i + wave) * 1024 + lane * 16]);
        }
    };

    // ---- repack geometry: granule g = (n2*10+w)*4+a, 640 over 256 thr ----
    int  rdE[3], wrO[3];
    bool gval[3];
#pragma unroll
    for (int it = 0; it < 3; ++it) {
        const int g = it * 256 + tid;
        gval[it] = (it < 2) || (g < 640);
        const int gg  = g < 640 ? g : 639;
        const int n2  = gg / 40;
        const int rem = gg - n2 * 40;
        const int w   = rem >> 2;
        const int a   = rem & 3;
        rdE[it] = (2 * n2) * XF32ROW + w * 64 + a * 16;   // even-row read
        wrO[it] = n2 * XSTRIDE_N2 + w * 64 + a * 16;      // bf16 granule write
    }

    // f32 LDS -> VERIFIED bf16 granule {even 4 floats, odd 4 floats}
    auto repack = [&]() {
#pragma unroll
        for (int it = 0; it < 3; ++it) if (gval[it]) {
            const f32x4 e = *reinterpret_cast<const f32x4*>(&xs[rdE[it]]);
            const f32x4 o = *reinterpret_cast<const f32x4*>(&xs[rdE[it] + XF32ROW]);
            uint4 u;
            u.x = pk2(e[0], e[1]); u.y = pk2(e[2], e[3]);
            u.z = pk2(o[0], o[1]); u.w = pk2(o[2], o[3]);
            *reinterpret_cast<uint4*>(&xs[XBFOFF + wrO[it]]) = u;
        }
    };

    // ---- prologue: async slab-0 stage + breg(kc=0..5) + gamma/beta ----
    issue(0);

    uint4 breg[2][6];                              // 48 VGPR
#pragma unroll
    for (int cp = 0; cp < 2; ++cp)
#pragma unroll
        for (int j = 0; j < 6; ++j)
            breg[cp][j] = ws[(ct0 + cp) * 768 + j * 64 + lane];

    float gmv[4], btv[4];
#pragma unroll
    for (int r = 0; r < 4; ++r) { gmv[r] = gp[r * 4 + dL]; btv[r] = bp[r * 4 + dL]; }

    __syncthreads();   // drains DMA -> slab-0 f32 image complete

    // per-lane bf16 A base (VERIFIED): offsets kn*2688 + k*64 + rt*256
    const unsigned char* ap =
        &xs[XBFOFF + q * XSTRIDE_N2 + (l15 >> 2) * 64 + (l15 & 3) * 16];

#pragma unroll
    for (int s = 0; s < 4; ++s) {
        // breg currently holds kc = fb..fb+5 (loaded at previous midpoint)
        const int fb = (s & 1) * 6;    // first-half kc base (compile-time)
        const int sb = 6 - fb;         // second-half kc base

        repack();
        __syncthreads();                           // bf16 ready; f32 buf free

        if (s < 3) {
            issue(s + 1);                          // async prefetch next slab
            __builtin_amdgcn_sched_barrier(0);     // pin issue before K-loop
        }

        f32x4 acc[2][2];
#pragma unroll
        for (int rt = 0; rt < 2; ++rt)
#pragma unroll
            for (int cp = 0; cp < 2; ++cp)
                acc[rt][cp] = (f32x4){0.f, 0.f, 0.f, 0.f};

        // ---- K-loop first half: kc = fb..fb+5 (breg resident) ----
#pragma unroll
        for (int j = 0; j < 6; ++j) {
            const int kc = fb + j;
            const int k  = kc >> 2;
            const int kn = kc & 3;
            bf16x8 afr[2];
#pragma unroll
            for (int rt = 0; rt < 2; ++rt) {
                frag_cast c;
                c.u = *reinterpret_cast<const uint4*>(
                    ap + kn * 2688 + k * 64 + rt * 256);
                afr[rt] = c.f;
            }
#pragma unroll
            for (int cp = 0; cp < 2; ++cp) {
                frag_cast bc; bc.u = breg[cp][j];
#pragma unroll
                for (int rt = 0; rt < 2; ++rt)
                    acc[rt][cp] = __builtin_amdgcn_mfma_f32_16x16x32_bf16(
                        afr[rt], bc.f, acc[rt][cp], 0, 0, 0);
            }
        }

        // ---- midpoint: breg <- kc = sb..sb+5 (L2-hot, 16 waves/CU hide) --
#pragma unroll
        for (int cp = 0; cp < 2; ++cp)
#pragma unroll
            for (int j = 0; j < 6; ++j)
                breg[cp][j] = ws[(ct0 + cp) * 768 + (sb + j) * 64 + lane];

        // ---- K-loop second half: kc = sb..sb+5 ----
#pragma unroll
        for (int j = 0; j < 6; ++j) {
            const int kc = sb + j;
            const int k  = kc >> 2;
            const int kn = kc & 3;
            bf16x8 afr[2];
#pragma unroll
            for (int rt = 0; rt < 2; ++rt) {
                frag_cast c;
                c.u = *reinterpret_cast<const uint4*>(
                    ap + kn * 2688 + k * 64 + rt * 256);
                afr[rt] = c.f;
            }
#pragma unroll
            for (int cp = 0; cp < 2; ++cp) {
                frag_cast bc; bc.u = breg[cp][j];
#pragma unroll
                for (int rt = 0; rt < 2; ++rt)
                    acc[rt][cp] = __builtin_amdgcn_mfma_f32_16x16x32_bf16(
                        afr[rt], bc.f, acc[rt][cp], 0, 0, 0);
            }
        }
        // NOTE: breg now holds kc = sb..sb+5 = next slab's first half. ✓

        // ---- fused LayerNorm (VERIFIED) + 4x4 quad transpose + dwordx4 ----
#pragma unroll
        for (int rt = 0; rt < 2; ++rt) {
            const int wv = W0 + s * 8 + rt * 4 + q;
#pragma unroll
            for (int cp = 0; cp < 2; ++cp) {
                const f32x4 v = acc[rt][cp];
                float ss = v[0] + v[1] + v[2] + v[3];
                float sq = v[0]*v[0] + v[1]*v[1] + v[2]*v[2] + v[3]*v[3];
                ss += __shfl_xor(ss, 1); ss += __shfl_xor(ss, 2);
                sq += __shfl_xor(sq, 1); sq += __shfl_xor(sq, 2);
                const float mu   = ss * (1.f / 16.f);
                const float var  = sq * (1.f / 16.f) - mu * mu;
                const float rstd = rsqrtf(var + 1e-5f);
                float y[4];
#pragma unroll
                for (int r = 0; r < 4; ++r)
                    y[r] = gmv[r] * (v[r] - mu) * rstd + btv[r];
                // 4x4 transpose over (dL, r): lane dL -> dout 4dL..4dL+3
#pragma unroll
                for (int mm = 1; mm <= 2; mm <<= 1) {
                    float p[4];
#pragma unroll
                    for (int r = 0; r < 4; ++r) p[r] = __shfl_xor(y[r], mm);
#pragma unroll
                    for (int r = 0; r < 4; ++r)
                        y[r] = ((dL ^ r) & mm) ? p[r ^ mm] : y[r];
                }
                if (wv < W_) {
                    const int m = (ct0 + cp) * 4 + msub;
                    float4* op = (float4*)(out +
                        ((size_t)(b * M_ + m) * W_ + wv) * D_ + dL * 4);
                    *op = make_float4(y[0], y[1], y[2], y[3]);
                }
            }
        }

        if (s < 3) __syncthreads();  // drains DMA (next f32 image) +
                                     // protects bf16 buf from next repack
    }
}

extern "C" void kernel_launch(void* const* d_in, const int* in_sizes, int n_in,
                              void* d_out, int out_size, void* d_ws, size_t ws_size,
                              hipStream_t stream) {
    const float* x  = (const float*)d_in[0];
    const float* w  = (const float*)d_in[1];
    const float* g  = (const float*)d_in[2];
    const float* be = (const float*)d_in[3];
    float* out = (float*)d_out;

    caps_setup<<<192, 64, 0, stream>>>(w, (uint2*)d_ws);
    caps_mfma<<<dim3(64, 16), 256, 0, stream>>>(
        x, (const uint4*)d_ws, g, be, out);
}